// Round 11
// baseline (4173.606 us; speedup 1.0000x reference)
//
#include <hip/hip_runtime.h>
#include <cstdint>
#include <cstddef>

#define BB 512   // batch
#define TT 512   // seq len
#define HH 100   // hidden
#define G4 400   // 4*H

// ---------------------------------------------------------------------------
// Recurrent kernel: full 512 steps of one layer in one launch.
// grid = 256 blocks x 448 threads (7 waves), 1 block/CU.
// Thread (p = tid>>3 unit-pair, s = tid&7): owns ALL 8 gate-rows of units
// {2p, 2p+1} over k-window [16s,16s+16), BOTH batch elems.
//   final combo of lane s: gate g = s>>1, elem e = s&1 (for both units).
// R=8 rows per h-read: 8 ds_read_b128 -> 256 FMA per step (2x round-10's
// ratio; LDS pipe was the invariant ~2000cy floor across rounds 3-10).
// Weights (128 floats) gathered from an LDS staging copy of Whh that is then
// clobbered -> compiler parks them in VGPR/AGPR, cannot remat (r6 precedent:
// flat FETCH, no scratch).
// Reduce: routing butterfly xor1 (elem), xor2 (g bit0), xor4 (g bit1);
// act in-lane; xor4 pairs i<->g,f<->o; xor2 ships i*tanh(g) to the f-lane.
// h layout [buf][w][kk*2+e], window stride 36 floats -> banks 4w, conflict-free.
// ---------------------------------------------------------------------------
template<bool IS_L0, bool WRITE_DROP>
__global__ __launch_bounds__(448, 1)
void rec_kernel(const float* __restrict__ x,       // [B][T] (layer0 input, IN=1)
                const float* __restrict__ xc,      // [T][B][400] (layers>0)
                const float* __restrict__ Whh_l,   // [400][100]
                const float* __restrict__ Wih0,    // [400] (layer0)
                const float* __restrict__ bih_l,   // [400] (layer0)
                const float* __restrict__ bhh_l,   // [400] (layer0)
                const float* __restrict__ dmask_l, // [B][T][100] (if WRITE_DROP)
                float* __restrict__ hdrop,         // [T][B][100] (if WRITE_DROP)
                float* __restrict__ st_h,          // [B][100]
                float* __restrict__ st_c)          // [B][100]
{
    __shared__ float Wst[G4 * HH];      // 160,000 B staging; clobbered after gather
    __shared__ float hbuf[2][8][36];    // [buf][window][kk*2+e], 2304 B

    const int tid = threadIdx.x;
    const int p   = tid >> 3;                  // 0..55 (unit pair)
    const int s   = tid & 7;
    const int g   = s >> 1;                    // final gate of this lane
    const int e   = s & 1;                     // final elem of this lane
    const bool active = (p < 50);
    const int pc  = active ? p : 49;
    const int b   = blockIdx.x * 2 + e;
    const bool isF = (g == 1);
    const bool isG = (g == 2);

    // --- stage Whh into LDS (coalesced float4) ---
    {
        const float4* src = (const float4*)Whh_l;
        float4* dst = (float4*)Wst;
        for (int i = tid; i < G4 * HH / 4; i += 448) dst[i] = src[i];
    }
    __syncthreads();

    // --- gather 8 rows x 16-k window into registers (zero past k=99) ---
    float w[4][2][16];
    #pragma unroll
    for (int gg = 0; gg < 4; ++gg) {
        #pragma unroll
        for (int du = 0; du < 2; ++du) {
            const float* rowp = &Wst[(size_t)(gg * HH + 2 * pc + du) * HH];
            #pragma unroll
            for (int q = 0; q < 4; ++q) {
                const int gk = 16 * s + 4 * q;
                float4 v = {0.f, 0.f, 0.f, 0.f};
                if (gk < HH) v = *(const float4*)(rowp + gk);   // 100%4==0: no partial quads
                w[gg][du][4*q+0] = v.x; w[gg][du][4*q+1] = v.y;
                w[gg][du][4*q+2] = v.z; w[gg][du][4*q+3] = v.w;
            }
        }
    }
    __syncthreads();

    // --- clobber staging (kills remat) + zero h double-buffers ---
    {
        float4* dst = (float4*)Wst;
        const float4 z = {0.f, 0.f, 0.f, 0.f};
        for (int i = tid; i < G4 * HH / 4; i += 448) dst[i] = z;
    }
    for (int i = tid; i < 2 * 8 * 36; i += 448) ((float*)hbuf)[i] = 0.f;

    // --- layer-0 input weights / fused bias for this lane's two rows ---
    float wx[2] = {0.f, 0.f}, bsv[2] = {0.f, 0.f};
    if (IS_L0) {
        #pragma unroll
        for (int du = 0; du < 2; ++du) {
            const int row = g * HH + 2 * pc + du;
            wx[du]  = Wih0[row];
            bsv[du] = bih_l[row] + bhh_l[row];
        }
    }

    float c2[2] = {0.f, 0.f}, hl[2] = {0.f, 0.f};
    __syncthreads();

    // --- rolling prefetch pointers ---
    const float* pA0 = xc ? (xc + (size_t)b * G4 + g * HH + 2 * pc + 0) : nullptr;
    const float* pA1 = xc ? (xc + (size_t)b * G4 + g * HH + 2 * pc + 1) : nullptr;
    const float* pm0 = dmask_l ? (dmask_l + (size_t)b * TT * HH + 2 * pc + 0) : nullptr;
    const float* pm1 = dmask_l ? (dmask_l + (size_t)b * TT * HH + 2 * pc + 1) : nullptr;
    const float* px  = x ? (x + (size_t)b * TT) : nullptr;

    float gin0 = 0.f, gin1 = 0.f, xv = 0.f, mk0 = 0.f, mk1 = 0.f;
    if (IS_L0) xv = px[0];
    else { gin0 = pA0[0]; gin1 = pA1[0]; }
    if (WRITE_DROP && isF && active) { mk0 = pm0[0]; mk1 = pm1[0]; }

    int cur = 0;
    for (int t = 0; t < TT; ++t) {
        const bool last = (t + 1 == TT);
        const float* nA0 = (!IS_L0 && !last) ? pA0 + (size_t)BB * G4 : pA0;
        const float* nA1 = (!IS_L0 && !last) ? pA1 + (size_t)BB * G4 : pA1;
        const float* nm0 = (WRITE_DROP && !last) ? pm0 + HH : pm0;
        const float* nm1 = (WRITE_DROP && !last) ? pm1 + HH : pm1;
        const float* npx = (IS_L0 && !last) ? px + 1 : px;

        // prefetch t+1
        float nxv = 0.f, ngin0 = 0.f, ngin1 = 0.f, nmk0 = 0.f, nmk1 = 0.f;
        if (IS_L0) nxv = npx[0];
        else { ngin0 = nA0[0]; ngin1 = nA1[0]; }
        if (WRITE_DROP && isF && active) { nmk0 = nm0[0]; nmk1 = nm1[0]; }

        if (IS_L0) {
            gin0 = fmaf(xv, wx[0], bsv[0]);
            gin1 = fmaf(xv, wx[1], bsv[1]);
        }

        // --- dot: 8 broadcast b128 reads, 256 FMA (8 rows x 16 k x 2 elems) ---
        float acc[4][2][2];
        #pragma unroll
        for (int gg = 0; gg < 4; ++gg)
            #pragma unroll
            for (int du = 0; du < 2; ++du)
                { acc[gg][du][0] = 0.f; acc[gg][du][1] = 0.f; }
        {
            const float4* hp = (const float4*)&hbuf[cur][s][0];
            #pragma unroll
            for (int i = 0; i < 8; ++i) {
                const float4 hv = hp[i];  // h[k][e0], h[k][e1], h[k+1][e0], h[k+1][e1]
                #pragma unroll
                for (int gg = 0; gg < 4; ++gg) {
                    #pragma unroll
                    for (int du = 0; du < 2; ++du) {
                        acc[gg][du][0] = fmaf(w[gg][du][2*i],   hv.x, acc[gg][du][0]);
                        acc[gg][du][1] = fmaf(w[gg][du][2*i],   hv.y, acc[gg][du][1]);
                        acc[gg][du][0] = fmaf(w[gg][du][2*i+1], hv.z, acc[gg][du][0]);
                        acc[gg][du][1] = fmaf(w[gg][du][2*i+1], hv.w, acc[gg][du][1]);
                    }
                }
            }
        }

        // --- stage 1 (xor1): resolve elem ---
        float v1[4][2];
        #pragma unroll
        for (int gg = 0; gg < 4; ++gg)
            #pragma unroll
            for (int du = 0; du < 2; ++du) {
                const float m = e ? acc[gg][du][1] : acc[gg][du][0];
                const float o = e ? acc[gg][du][0] : acc[gg][du][1];
                v1[gg][du] = m + __shfl_xor(o, 1);
            }
        // --- stage 2 (xor2): resolve gate bit0 ---
        const int bt0 = (s >> 1) & 1;
        float v2[2][2];
        #pragma unroll
        for (int gh = 0; gh < 2; ++gh)
            #pragma unroll
            for (int du = 0; du < 2; ++du) {
                const float m = bt0 ? v1[gh*2+1][du] : v1[gh*2+0][du];
                const float o = bt0 ? v1[gh*2+0][du] : v1[gh*2+1][du];
                v2[gh][du] = m + __shfl_xor(o, 2);
            }
        // --- stage 3 (xor4): resolve gate bit1 ---
        const int bt1 = (s >> 2) & 1;
        float tot[2];
        #pragma unroll
        for (int du = 0; du < 2; ++du) {
            const float m = bt1 ? v2[1][du] : v2[0][du];
            const float o = bt1 ? v2[0][du] : v2[1][du];
            tot[du] = m + __shfl_xor(o, 4);
        }
        tot[0] += gin0;
        tot[1] += gin1;

        // --- activations (gate g: 2=tanh else sigmoid) ---
        float act[2], rc4[2], igv[2];
        #pragma unroll
        for (int du = 0; du < 2; ++du) {
            const float E  = __expf(isG ? (tot[du] + tot[du]) : (-tot[du]));
            const float rr = 1.f / (1.f + E);
            act[du] = isG ? fmaf(-2.f, rr, 1.f) : rr;
        }
        #pragma unroll
        for (int du = 0; du < 2; ++du) rc4[du] = __shfl_xor(act[du], 4);
        #pragma unroll
        for (int du = 0; du < 2; ++du) igv[du] = __shfl_xor(act[du] * rc4[du], 2);

        const int nxt = cur ^ 1;
        if (isF && active) {   // f-lane: act=sig(f), rc4=sig(o), igv=sig(i)*tanh(g)
            #pragma unroll
            for (int du = 0; du < 2; ++du) {
                c2[du] = fmaf(act[du], c2[du], igv[du]);
                const float Ec = __expf(c2[du] + c2[du]);
                const float th = 1.f - 2.f / (Ec + 1.f);
                const float h  = rc4[du] * th;
                hl[du] = h;
                const int u = 2 * pc + du;
                hbuf[nxt][u >> 4][(u & 15) * 2 + e] = h;
            }
            if (WRITE_DROP) {
                hdrop[((size_t)t * BB + b) * HH + 2 * pc + 0] = hl[0] * mk0 * 2.f;
                hdrop[((size_t)t * BB + b) * HH + 2 * pc + 1] = hl[1] * mk1 * 2.f;
            }
        }
        __syncthreads();
        cur = nxt;
        gin0 = ngin0; gin1 = ngin1; xv = nxv; mk0 = nmk0; mk1 = nmk1;
        pA0 = nA0; pA1 = nA1; pm0 = nm0; pm1 = nm1; px = npx;
    }

    if (isF && active) {
        #pragma unroll
        for (int du = 0; du < 2; ++du) {
            st_h[(size_t)b * HH + 2 * pc + du] = hl[du];
            st_c[(size_t)b * HH + 2 * pc + du] = c2[du];
        }
    }
}

// ---------------------------------------------------------------------------
// Input-contribution GEMM for layers 1..3 (measured ~280us/launch):
// xc[m][n] = sum_k A[m][k]*W[n][k] + (bih[n]+bhh[n]), M=T*B=262144, N=400,K=100
// tile 128(M)x64(N), 256 threads, 8x4 microtile, LDS 80 KB -> 2 blocks/CU.
// ---------------------------------------------------------------------------
__global__ __launch_bounds__(256, 2)
void xc_gemm(const float* __restrict__ A,     // [M][100]
             const float* __restrict__ W,     // [400][100]
             const float* __restrict__ bih_l, // [400]
             const float* __restrict__ bhh_l, // [400]
             float* __restrict__ xc)          // [M][400]
{
    __shared__ float At[HH][132];
    __shared__ float Bt[HH][68];

    const int tid = threadIdx.x;
    const int n0  = blockIdx.x * 64;
    const size_t m0 = (size_t)blockIdx.y * 128;

    for (int s = tid; s < 128 * 25; s += 256) {
        const int r = s / 25, kq = s - r * 25;
        const float4 v = *(const float4*)&A[(m0 + r) * HH + kq * 4];
        At[kq * 4 + 0][r] = v.x; At[kq * 4 + 1][r] = v.y;
        At[kq * 4 + 2][r] = v.z; At[kq * 4 + 3][r] = v.w;
    }
    for (int s = tid; s < 64 * 25; s += 256) {
        const int r = s / 25, kq = s - r * 25;
        const int col = n0 + r;
        float4 v = {0.f, 0.f, 0.f, 0.f};
        if (col < G4) v = *(const float4*)&W[(size_t)col * HH + kq * 4];
        Bt[kq * 4 + 0][r] = v.x; Bt[kq * 4 + 1][r] = v.y;
        Bt[kq * 4 + 2][r] = v.z; Bt[kq * 4 + 3][r] = v.w;
    }
    __syncthreads();

    const int tx = tid & 15;   // col group: cols tx*4..+3
    const int ty = tid >> 4;   // row group: rows ty*8..+7
    float acc[8][4];
    #pragma unroll
    for (int i = 0; i < 8; ++i)
        #pragma unroll
        for (int jj = 0; jj < 4; ++jj) acc[i][jj] = 0.f;

    #pragma unroll 4
    for (int k = 0; k < HH; ++k) {
        const float4 a0 = *(const float4*)&At[k][ty * 8];
        const float4 a1 = *(const float4*)&At[k][ty * 8 + 4];
        const float4 bv = *(const float4*)&Bt[k][tx * 4];
        const float av[8] = {a0.x, a0.y, a0.z, a0.w, a1.x, a1.y, a1.z, a1.w};
        #pragma unroll
        for (int i = 0; i < 8; ++i) {
            acc[i][0] = fmaf(av[i], bv.x, acc[i][0]);
            acc[i][1] = fmaf(av[i], bv.y, acc[i][1]);
            acc[i][2] = fmaf(av[i], bv.z, acc[i][2]);
            acc[i][3] = fmaf(av[i], bv.w, acc[i][3]);
        }
    }

    const int col = n0 + tx * 4;
    if (col < G4) {
        const float4 u = *(const float4*)&bih_l[col];
        const float4 v = *(const float4*)&bhh_l[col];
        const float4 bias = {u.x + v.x, u.y + v.y, u.z + v.z, u.w + v.w};
        #pragma unroll
        for (int i = 0; i < 8; ++i) {
            const size_t r = m0 + ty * 8 + i;
            float4 o = {acc[i][0] + bias.x, acc[i][1] + bias.y,
                        acc[i][2] + bias.z, acc[i][3] + bias.w};
            *(float4*)&xc[r * G4 + col] = o;
        }
    }
}

// ---------------------------------------------------------------------------
__global__ __launch_bounds__(256)
void out_kernel(const float* __restrict__ st_h3,  // [B][100]
                const float* __restrict__ Wout,   // [100]
                const float* __restrict__ bout,   // [1]
                float* __restrict__ out)          // [B]
{
    const int b = blockIdx.x * 256 + threadIdx.x;
    if (b < BB) {
        float sum = bout[0];
        #pragma unroll 4
        for (int k = 0; k < HH; ++k)
            sum = fmaf(st_h3[(size_t)b * HH + k], Wout[k], sum);
        out[b] = sum;
    }
}

// ---------------------------------------------------------------------------
extern "C" void kernel_launch(void* const* d_in, const int* in_sizes, int n_in,
                              void* d_out, int out_size, void* d_ws, size_t ws_size,
                              hipStream_t stream)
{
    const float* x     = (const float*)d_in[0];  // [512][512][1]
    const float* Wih0  = (const float*)d_in[1];  // [400][1]
    const float* WihR  = (const float*)d_in[2];  // [3][400][100]
    const float* Whh   = (const float*)d_in[3];  // [4][400][100]
    const float* bih   = (const float*)d_in[4];  // [4][400]
    const float* bhh   = (const float*)d_in[5];  // [4][400]
    const float* Wout  = (const float*)d_in[6];  // [1][100]
    const float* bout  = (const float*)d_in[7];  // [1]
    const float* dmask = (const float*)d_in[8];  // [3][512][512][100]
    float* out = (float*)d_out;

    // ws layout (floats): ~526 MB of the 1200 MB workspace
    float* ws    = (float*)d_ws;
    float* xcb   = ws;                                  // T*B*400
    float* hdrop = xcb + (size_t)TT * BB * G4;          // T*B*100
    float* sth   = hdrop + (size_t)TT * BB * HH;        // 4*B*100
    float* stc   = sth + (size_t)4 * BB * HH;           // 4*B*100

    const dim3 rgrid(BB / 2), rblk(448);
    const dim3 ggrid(7, (TT * BB) / 128), gblk(256);

    // layer 0 (input dim 1 fused into rec)
    rec_kernel<true, true><<<rgrid, rblk, 0, stream>>>(
        x, nullptr, Whh, Wih0, bih, bhh, dmask,
        hdrop, sth, stc);
    // layers 1..3
    for (int l = 1; l < 4; ++l) {
        xc_gemm<<<ggrid, gblk, 0, stream>>>(
            hdrop, WihR + (size_t)(l - 1) * G4 * HH,
            bih + l * G4, bhh + l * G4, xcb);
        if (l < 3) {
            rec_kernel<false, true><<<rgrid, rblk, 0, stream>>>(
                nullptr, xcb, Whh + (size_t)l * G4 * HH,
                nullptr, nullptr, nullptr,
                dmask + (size_t)l * BB * TT * HH,
                hdrop, sth + (size_t)l * BB * HH, stc + (size_t)l * BB * HH);
        } else {
            rec_kernel<false, false><<<rgrid, rblk, 0, stream>>>(
                nullptr, xcb, Whh + (size_t)l * G4 * HH,
                nullptr, nullptr, nullptr,
                nullptr,
                nullptr, sth + (size_t)l * BB * HH, stc + (size_t)l * BB * HH);
        }
    }
    out_kernel<<<dim3(2), dim3(256), 0, stream>>>(sth + (size_t)3 * BB * HH, Wout, bout, out);
}